// Round 9
// baseline (695.133 us; speedup 1.0000x reference)
//
#include <hip/hip_runtime.h>
#include <hip/hip_fp16.h>
#include <cstdint>
#include <cstddef>

typedef _Float16 half8 __attribute__((ext_vector_type(8)));
typedef _Float16 half4 __attribute__((ext_vector_type(4)));
typedef float floatx4 __attribute__((ext_vector_type(4)));
typedef float floatx16 __attribute__((ext_vector_type(16)));

#define N_TOK 8192
#define DIM   1024

#define EPI_F32   0   // C fp32 = acc                          (S = q k^T)
#define EPI_PART  1   // C fp32 partial at [row*ldc + bz*DIM + col]  (PV split-K)

#define FENCE_BARRIER() asm volatile("s_barrier" ::: "memory")
#define WAIT_VM4()      asm volatile("s_waitcnt vmcnt(4)" ::: "memory")
#define WAIT_VM0()      asm volatile("s_waitcnt vmcnt(0)" ::: "memory")

__device__ __forceinline__ void async_tile16(const _Float16* gp, _Float16* lp) {
    __builtin_amdgcn_global_load_lds(
        (const __attribute__((address_space(1))) void*)gp,
        (__attribute__((address_space(3))) void*)lp, 16, 0, 0);
}

// ---------------------------------------------------------------------------
// 256x256 tile, BK=64, 8 waves (2M x 4N), 512 threads, 4 phases / 2 K-tiles
// (v7 schedule, hazard ledger unchanged).
// v8: MFMA shape 16x16x32 -> 32x32x16. Same FLOPs in HALF the instructions
// at a 15% higher ubench ceiling (2382 vs 2075 TF) -> less issue pressure.
// Wave tile 128x64 = 4 m-tiles x 2 n-tiles of 32x32; per K-tile 32 MFMAs
// split P-a {mt0-1 + all B frags} / P-b {mt2-3} matching the v7 buffer-free
// discipline. Fragment & C/D layouts are the m74/m101-verified 32x32 ones
// (identical to gemm_qkv below / the original round-0 kernel: 0 bank
// conflicts at this LDS swizzle).
// NT GEMM: C[m][n] = sum_k A[m][k]*B[n][k].
// FOLD: logical K = 2*1024; A = q_hi for kt<16 else q_lo; kt clamped.
// ---------------------------------------------------------------------------
template<int EPI, bool FOLD, bool REMAP, int LDA, int LDB>
__global__ __launch_bounds__(512)
void gemm8(const _Float16* __restrict__ Ahi, const _Float16* __restrict__ Alo,
           const _Float16* __restrict__ B, int ntiles,
           float* __restrict__ C, int ldc)
{
    __shared__ _Float16 smem[65536];          // 128 KiB

    int bx = blockIdx.x, by = blockIdx.y, bz = blockIdx.z;
    if constexpr (REMAP) {
        const int gx = gridDim.x, gy = gridDim.y;
        const int gxy = gx * gy;
        const int nb = gxy * gridDim.z;
        const int bid = bz * gxy + by * gx + bx;
        const int nid = (bid & 7) * (nb >> 3) + (bid >> 3);
        bx = nid % gx; by = (nid / gx) % gy; bz = nid / gxy;
    }

    const int tid  = threadIdx.x;
    const int lane = tid & 63;
    const int w    = tid >> 6;
    const int wm   = w >> 2;                  // 0..1 -> 128-row half
    const int wn   = w & 3;                   // 0..3 -> 64-col slice
    const int l31  = lane & 31;
    const int l32  = lane >> 5;               // 0..1
    const int row0 = by * 256;
    const int col0 = bx * 256;
    const int kbeg_t = FOLD ? 0 : bz * ntiles;

    const int r_s = tid >> 3;                 // staging row within 64-row pass
    const int j_s = tid & 7;                  // staging 16B chunk

    _Float16* A0 = smem;                      // buf0 A (256x64)
    _Float16* B0 = smem + 16384;              // buf0 B
    _Float16* A1 = smem + 32768;              // buf1 A
    _Float16* B1 = smem + 49152;              // buf1 B

    floatx16 acc[4][2];
#pragma unroll
    for (int mt = 0; mt < 4; mt++)
#pragma unroll
        for (int nt = 0; nt < 2; nt++)
#pragma unroll
            for (int e = 0; e < 16; e++) acc[mt][nt][e] = 0.f;

    half8 af[2][4], bf[2][4];                 // [tile][ks], accessed by name only

    // global source pointer for A/B at K-tile kt (clamped; FOLD selects hi/lo)
    auto asrc = [&](int kt) -> const _Float16* {
        int ktc = kt > ntiles - 1 ? ntiles - 1 : kt;
        if constexpr (FOLD) {
            const _Float16* base = (ktc < 16) ? Ahi : Alo;
            return base + (size_t)row0 * LDA + (ktc & 15) * 64;
        } else {
            return Ahi + (size_t)row0 * LDA + (size_t)(kbeg_t + ktc) * 64;
        }
    };
    auto bsrc = [&](int kt) -> const _Float16* {
        int ktc = kt > ntiles - 1 ? ntiles - 1 : kt;
        const int kk = FOLD ? (ktc & 15) : (kbeg_t + ktc);
        return B + (size_t)col0 * LDB + (size_t)kk * 64;
    };

    // stage one 128x64 half-tile (2 x global_load_lds dwordx4 per thread)
    auto stageA = [&](const _Float16* tile, int half, _Float16* reg) {
#pragma unroll
        for (int p = 0; p < 2; p++) {
            const int r  = half * 128 + p * 64 + r_s;
            const int jg = j_s ^ ((r >> 1) & 7);
            async_tile16(tile + (size_t)r * LDA + jg * 8, reg + r * 64 + j_s * 8);
        }
    };
    auto stageB = [&](const _Float16* tile, int half, _Float16* reg) {
#pragma unroll
        for (int p = 0; p < 2; p++) {
            const int r  = half * 128 + p * 64 + r_s;
            const int jg = j_s ^ ((r >> 1) & 7);
            async_tile16(tile + (size_t)r * LDB + jg * 8, reg + r * 64 + j_s * 8);
        }
    };

    // 32x32x16 fragment reads: lane reads 8 fp16 at row (tile*32 + l31),
    // k = ks*16 + l32*8 -> 16B chunk cb = ks*2 + l32, XOR-swizzled by row.
    auto ldsB2 = [&](const _Float16* Bb) {               // all B: nt 0..1 x ks 0..3
#pragma unroll
        for (int nt = 0; nt < 2; nt++)
#pragma unroll
            for (int ks = 0; ks < 4; ks++) {
                const int rr = wn * 64 + nt * 32 + l31;
                const int cb = ks * 2 + l32;
                bf[nt][ks] = *(const half8*)&Bb[rr * 64 + ((cb ^ ((rr >> 1) & 7)) << 3)];
            }
    };
    auto ldsA2 = [&](const _Float16* Ab, int mbase) {    // m-tiles mbase..mbase+1
#pragma unroll
        for (int m2 = 0; m2 < 2; m2++)
#pragma unroll
            for (int ks = 0; ks < 4; ks++) {
                const int rr = wm * 128 + (mbase + m2) * 32 + l31;
                const int cb = ks * 2 + l32;
                af[m2][ks] = *(const half8*)&Ab[rr * 64 + ((cb ^ ((rr >> 1) & 7)) << 3)];
            }
    };
    // 16 MFMA (32x32x16): m-tiles mbase..mbase+1 x nt 0..1 x ks 0..3.
    // ks outermost -> same-acc reuse 4 insts apart.
    auto quadA = [&](int mbase) {
        __builtin_amdgcn_s_setprio(1);
#pragma unroll
        for (int ks = 0; ks < 4; ks++)
#pragma unroll
            for (int m2 = 0; m2 < 2; m2++)
#pragma unroll
                for (int nt = 0; nt < 2; nt++)
                    acc[mbase + m2][nt] =
                        __builtin_amdgcn_mfma_f32_32x32x16_f16(
                            af[m2][ks], bf[nt][ks], acc[mbase + m2][nt], 0, 0, 0);
        __builtin_amdgcn_s_setprio(0);
    };

    // ---- prologue: buf0 <- kt0 full, buf1.B <- kt1 ----
    stageB(bsrc(0), 0, B0); stageB(bsrc(0), 1, B0);
    stageA(asrc(0), 0, A0); stageA(asrc(0), 1, A0);
    stageB(bsrc(1), 0, B1); stageB(bsrc(1), 1, B1);
    WAIT_VM4();                                // buf0 landed; B1(t1) x4 in flight
    FENCE_BARRIER();

    const int NIc = ntiles >> 1;
    for (int i = 0; i < NIc; i++) {
        const int t1 = 2 * i + 1, t2 = 2 * i + 2, t3 = 2 * i + 3;
        // P1: stage A1(t1) full; read B0 all + A0 mt0-1; 16 MFMA
        stageA(asrc(t1), 0, A1); stageA(asrc(t1), 1, A1);
        ldsB2(B0); ldsA2(A0, 0);
        quadA(0);
        FENCE_BARRIER();
        // P2: stage B0(t2) full; read A0 mt2-3; 16 MFMA; gate {B1,A1}(t1)
        stageB(bsrc(t2), 0, B0); stageB(bsrc(t2), 1, B0);
        ldsA2(A0, 2);
        quadA(2);
        WAIT_VM4(); FENCE_BARRIER();
        // P3: stage A0(t2) full; read B1 all + A1 mt0-1; 16 MFMA
        stageA(asrc(t2), 0, A0); stageA(asrc(t2), 1, A0);
        ldsB2(B1); ldsA2(A1, 0);
        quadA(0);
        FENCE_BARRIER();
        // P4: stage B1(t3) full; read A1 mt2-3; 16 MFMA; gate {B0,A0}(t2)
        stageB(bsrc(t3), 0, B1); stageB(bsrc(t3), 1, B1);
        ldsA2(A1, 2);
        quadA(2);
        WAIT_VM4(); FENCE_BARRIER();
    }
    WAIT_VM0();

    // epilogue. 32x32 C/D layout (verified m74/m101): col = lane&31,
    // row = (reg&3) + 8*(reg>>2) + 4*(lane>>5)
#pragma unroll
    for (int mt = 0; mt < 4; mt++) {
#pragma unroll
        for (int nt = 0; nt < 2; nt++) {
            const int col  = col0 + wn * 64 + nt * 32 + l31;
            const int base = row0 + wm * 128 + mt * 32 + 4 * l32;
#pragma unroll
            for (int g = 0; g < 4; g++) {
                const int rowb = base + 8 * g;            // rows rowb..rowb+3, regs 4g..4g+3
#pragma unroll
                for (int r2 = 0; r2 < 4; r2++) {
                    const int row = rowb + r2;
                    const float v = acc[mt][nt][4 * g + r2];
                    if constexpr (EPI == EPI_F32) {
                        C[(size_t)row * ldc + col] = v;
                    } else {
                        C[(size_t)row * ldc + (size_t)bz * DIM + col] = v;
                    }
                }
            }
        }
    }
}

// ---------------------------------------------------------------------------
// Fused QKV projection (proven structure): grid.z = unit (0=q HILO, 1=k HI,
// 2=v VT). B = stacked [3*DIM][DIM] fp16 weights. 128x128 tile, BK=64.
// ---------------------------------------------------------------------------
template<int BM, int BN, int BK>
__global__ __launch_bounds__(256)
void gemm_qkv(const _Float16* __restrict__ Ehi, const _Float16* __restrict__ Elo,
              const _Float16* __restrict__ W,
              _Float16* __restrict__ qhi, _Float16* __restrict__ qlo,
              _Float16* __restrict__ khi, _Float16* __restrict__ vtr,
              const float* __restrict__ bq, const float* __restrict__ bk,
              const float* __restrict__ bv)
{
    constexpr int MI = BM / 64;
    constexpr int NI = BN / 64;
    constexpr int CPR = BK / 8;
    constexpr int SW  = CPR - 1;
    constexpr int RPP = 2048 / BK;
    constexpr int IA  = BM * BK / 2048;
    constexpr int IB  = BN * BK / 2048;
    constexpr int A_ELTS = BM * BK;
    constexpr int B_ELTS = BN * BK;
    __shared__ _Float16 smem[2 * A_ELTS + B_ELTS];
    constexpr int tAhi = 0;
    constexpr int tAlo = A_ELTS;
    constexpr int tB   = 2 * A_ELTS;

    int bx = blockIdx.x, by = blockIdx.y, bz = blockIdx.z;
    {
        const int gx = gridDim.x, gy = gridDim.y;
        const int gxy = gx * gy;
        const int nb = gxy * gridDim.z;
        const int bid = bz * gxy + by * gx + bx;
        const int nid = (bid & 7) * (nb >> 3) + (bid >> 3);
        bx = nid % gx; by = (nid / gx) % gy; bz = nid / gxy;
    }
    const int unit = bz;
    const bool dolo = (unit < 2);

    const int tid  = threadIdx.x;
    const int row0 = by * BM;
    const int col0 = bx * BN;
    const int lane = tid & 63;
    const int w    = tid >> 6;
    const int wm   = w & 1, wn = w >> 1;
    const int l31  = lane & 31, lhi = lane >> 5;

    floatx16 acc[MI][NI];
#pragma unroll
    for (int mi = 0; mi < MI; mi++)
#pragma unroll
        for (int ni = 0; ni < NI; ni++)
#pragma unroll
            for (int e = 0; e < 16; e++) acc[mi][ni][e] = 0.f;

    const int r_s = tid / CPR;
    const int j_s = tid % CPR;
    const size_t brow0 = (size_t)(unit * DIM + col0);

    for (int k0 = 0; k0 < DIM; k0 += BK) {
        __syncthreads();
#pragma unroll
        for (int i = 0; i < IA; i++) {
            const int r = i * RPP + r_s;
            const int jg = j_s ^ ((r >> 1) & SW);
            async_tile16(Ehi + (size_t)(row0 + r) * DIM + k0 + jg * 8,
                         smem + tAhi + (i * 256 + tid) * 8);
            if (dolo)
                async_tile16(Elo + (size_t)(row0 + r) * DIM + k0 + jg * 8,
                             smem + tAlo + (i * 256 + tid) * 8);
        }
#pragma unroll
        for (int i = 0; i < IB; i++) {
            const int r = i * RPP + r_s;
            const int jg = j_s ^ ((r >> 1) & SW);
            async_tile16(W + (brow0 + r) * DIM + k0 + jg * 8,
                         smem + tB + (i * 256 + tid) * 8);
        }
        __syncthreads();

#pragma unroll
        for (int ks = 0; ks < BK / 16; ks++) {
            half8 af[MI], bf[NI], al[MI];
            const int cb = ks * 2 + lhi;
#pragma unroll
            for (int mi = 0; mi < MI; mi++) {
                const int r = wm * (BM / 2) + mi * 32 + l31;
                const int cj = (cb ^ ((r >> 1) & SW)) * 8;
                af[mi] = *(half8*)&smem[tAhi + r * BK + cj];
                if (dolo) al[mi] = *(half8*)&smem[tAlo + r * BK + cj];
            }
#pragma unroll
            for (int ni = 0; ni < NI; ni++) {
                const int r = wn * (BN / 2) + ni * 32 + l31;
                const int cj = (cb ^ ((r >> 1) & SW)) * 8;
                bf[ni] = *(half8*)&smem[tB + r * BK + cj];
            }
#pragma unroll
            for (int mi = 0; mi < MI; mi++)
#pragma unroll
                for (int ni = 0; ni < NI; ni++)
                    acc[mi][ni] = __builtin_amdgcn_mfma_f32_32x32x16_f16(af[mi], bf[ni], acc[mi][ni], 0, 0, 0);
            if (dolo) {
#pragma unroll
                for (int mi = 0; mi < MI; mi++)
#pragma unroll
                    for (int ni = 0; ni < NI; ni++)
                        acc[mi][ni] = __builtin_amdgcn_mfma_f32_32x32x16_f16(al[mi], bf[ni], acc[mi][ni], 0, 0, 0);
            }
        }
    }

    const float* bias = (unit == 0) ? bq : (unit == 1) ? bk : bv;
#pragma unroll
    for (int mi = 0; mi < MI; mi++) {
#pragma unroll
        for (int ni = 0; ni < NI; ni++) {
            const int colg = col0 + wn * (BN / 2) + ni * 32 + l31;
            const float bb = bias[colg];
            const int base = row0 + wm * (BM / 2) + mi * 32 + 4 * lhi;
#pragma unroll
            for (int g = 0; g < 4; g++) {
                const int rowb = base + 8 * g;
                if (unit == 2) {
                    half4 hv;
#pragma unroll
                    for (int r2 = 0; r2 < 4; r2++) hv[r2] = (_Float16)(acc[mi][ni][4 * g + r2] + bb);
                    *(half4*)&vtr[(size_t)colg * N_TOK + rowb] = hv;
                } else {
#pragma unroll
                    for (int r2 = 0; r2 < 4; r2++) {
                        const int rowg = rowb + r2;
                        const float t = acc[mi][ni][4 * g + r2] + bb;
                        const _Float16 hi = (_Float16)t;
                        if (unit == 0) {
                            qhi[(size_t)rowg * DIM + colg] = hi;
                            qlo[(size_t)rowg * DIM + colg] = (_Float16)(t - (float)hi);
                        } else {
                            khi[(size_t)rowg * DIM + colg] = hi;
                        }
                    }
                }
            }
        }
    }
}

// fp32 -> fp16 hi (+lo) pre-split. grid.y = unit: 0..7 = E chunks, 8/9/10 = Wq/Wk/Wv.
__global__ __launch_bounds__(256)
void split_inputs(const float* __restrict__ E,
                  const float* __restrict__ Wq, const float* __restrict__ Wk, const float* __restrict__ Wv,
                  _Float16* __restrict__ Ehi, _Float16* __restrict__ Elo,
                  _Float16* __restrict__ Wqh, _Float16* __restrict__ Wkh, _Float16* __restrict__ Wvh)
{
    const int u = blockIdx.y;
    const size_t idx = ((size_t)blockIdx.x * 256 + threadIdx.x) * 4;
    const size_t MM = (size_t)DIM * DIM;
    const float* src; _Float16* dhi; _Float16* dlo = nullptr;
    if (u < 8)      { src = E + u * MM;  dhi = Ehi + u * MM; dlo = Elo + u * MM; }
    else if (u == 8){ src = Wq; dhi = Wqh; }
    else if (u == 9){ src = Wk; dhi = Wkh; }
    else            { src = Wv; dhi = Wvh; }
    const float4 f = *(const float4*)(src + idx);
    half4 hh;
    hh[0] = (_Float16)f.x; hh[1] = (_Float16)f.y; hh[2] = (_Float16)f.z; hh[3] = (_Float16)f.w;
    *(half4*)(dhi + idx) = hh;
    if (u < 8) {
        half4 hl;
        hl[0] = (_Float16)(f.x - (float)hh[0]); hl[1] = (_Float16)(f.y - (float)hh[1]);
        hl[2] = (_Float16)(f.z - (float)hh[2]); hl[3] = (_Float16)(f.w - (float)hh[3]);
        *(half4*)(dlo + idx) = hl;
    }
}

// One block per row. Row held in REGISTERS (8 x float4 per thread, static
// indices). P = exp(s-m) fp16 in place, inv_l = 1/sum.
__global__ __launch_bounds__(256)
void softmax_rows(float* __restrict__ S, float* __restrict__ inv_l)
{
    __shared__ float red[4];
    const int tid = threadIdx.x;
    float* row = S + (size_t)blockIdx.x * N_TOK;

    float4 v0, v1, v2, v3, v4, v5, v6, v7;
    float mx = -3.0e38f;
#define LOADMAX(VV, I) \
    VV = ((const float4*)row)[(I) * 256 + tid]; \
    mx = fmaxf(mx, fmaxf(fmaxf(VV.x, VV.y), fmaxf(VV.z, VV.w)));
    LOADMAX(v0, 0) LOADMAX(v1, 1) LOADMAX(v2, 2) LOADMAX(v3, 3)
    LOADMAX(v4, 4) LOADMAX(v5, 5) LOADMAX(v6, 6) LOADMAX(v7, 7)
#undef LOADMAX
#pragma unroll
    for (int off = 32; off > 0; off >>= 1) mx = fmaxf(mx, __shfl_down(mx, off));
    if ((tid & 63) == 0) red[tid >> 6] = mx;
    __syncthreads();
    mx = fmaxf(fmaxf(red[0], red[1]), fmaxf(red[2], red[3]));
    __syncthreads();

    float sum = 0.f;
    _Float16* prow = (_Float16*)row;
#define EXPSTORE(VV, I) { \
    const float e0 = __expf(VV.x - mx), e1 = __expf(VV.y - mx); \
    const float e2 = __expf(VV.z - mx), e3 = __expf(VV.w - mx); \
    sum += (e0 + e1) + (e2 + e3); \
    half4 h; h[0] = (_Float16)e0; h[1] = (_Float16)e1; h[2] = (_Float16)e2; h[3] = (_Float16)e3; \
    ((half4*)prow)[(I) * 256 + tid] = h; }
    EXPSTORE(v0, 0) EXPSTORE(v1, 1) EXPSTORE(v2, 2) EXPSTORE(v3, 3)
    EXPSTORE(v4, 4) EXPSTORE(v5, 5) EXPSTORE(v6, 6) EXPSTORE(v7, 7)
#undef EXPSTORE
#pragma unroll
    for (int off = 32; off > 0; off >>= 1) sum += __shfl_down(sum, off);
    if ((tid & 63) == 0) red[tid >> 6] = sum;
    __syncthreads();
    if (tid == 0) inv_l[blockIdx.x] = 1.f / (red[0] + red[1] + red[2] + red[3]);
}

// out[r][c] = invl[r] * sum_z partial[z][r][c]; partials in float offsets [4096,8192)
// of each Sc row. One block per row.
__global__ __launch_bounds__(256)
void reduce_pv(const float* __restrict__ Sc, const float* __restrict__ invl,
               float* __restrict__ out)
{
    const int r  = blockIdx.x;
    const int c4 = threadIdx.x;
    const float* p = Sc + (size_t)r * N_TOK + N_TOK / 2 + (size_t)c4 * 4;
    float4 s = *(const float4*)p;
#pragma unroll
    for (int z = 1; z < 4; z++) {
        const float4 t = *(const float4*)(p + (size_t)z * DIM);
        s.x += t.x; s.y += t.y; s.z += t.z; s.w += t.w;
    }
    const float iv = invl[r];
    float4 o; o.x = s.x * iv; o.y = s.y * iv; o.z = s.z * iv; o.w = s.w * iv;
    *(float4*)(out + (size_t)r * DIM + (size_t)c4 * 4) = o;
}

extern "C" void kernel_launch(void* const* d_in, const int* in_sizes, int n_in,
                              void* d_out, int out_size, void* d_ws, size_t ws_size,
                              hipStream_t stream)
{
    const float* E  = (const float*)d_in[0];
    const float* Wq = (const float*)d_in[1];
    const float* bq = (const float*)d_in[2];
    const float* Wk = (const float*)d_in[3];
    const float* bk = (const float*)d_in[4];
    const float* Wv = (const float*)d_in[5];
    const float* bv = (const float*)d_in[6];
    float* out = (float*)d_out;

    char* ws = (char*)d_ws;
    const size_t SZ = (size_t)N_TOK * DIM * sizeof(_Float16);   // 16 MiB
    const size_t WW = (size_t)DIM * DIM * sizeof(_Float16);     // 2 MiB
    _Float16* q_hi = (_Float16*)(ws);
    _Float16* q_lo = (_Float16*)(ws + SZ);
    _Float16* k_hi = (_Float16*)(ws + 2 * SZ);
    _Float16* vt   = (_Float16*)(ws + 3 * SZ);
    float*    invl = (float*)(ws + 4 * SZ);
    char*     scratch = ws + 4 * SZ + 65536;
    _Float16* Ehi = (_Float16*)(scratch);
    _Float16* Elo = (_Float16*)(scratch + SZ);
    _Float16* Wqh = (_Float16*)(scratch + 2 * SZ);              // Wqh,Wkh,Wvh contiguous
    _Float16* Wkh = (_Float16*)(scratch + 2 * SZ + WW);
    _Float16* Wvh = (_Float16*)(scratch + 2 * SZ + 2 * WW);
    float*    Sc  = (float*)(scratch);
    const size_t esplit_bytes = 2 * SZ + 3 * WW;
    const size_t base = 4 * SZ + 65536;

    int NC = 256;
    const int cands[6] = {8192, 4096, 2048, 1024, 512, 256};
    for (int i = 0; i < 6; i++) {
        size_t sc = (size_t)cands[i] * N_TOK * 4;
        size_t need = base + (sc > esplit_bytes ? sc : esplit_bytes);
        if (ws_size >= need) { NC = cands[i]; break; }
    }

    const dim3 blk(256, 1, 1);
    const dim3 blk512(512, 1, 1);
    constexpr int KS = 4;                  // PV split-K factor

    // ---- pre-split: E -> hi/lo fp16, W -> hi fp16 ----
    split_inputs<<<dim3(DIM * DIM / 1024, 11, 1), blk, 0, stream>>>(
        E, Wq, Wk, Wv, Ehi, Elo, Wqh, Wkh, Wvh);

    // ---- fused QKV projection: one dispatch, 3 units on grid.z ----
    gemm_qkv<128, 128, 64><<<dim3(DIM / 128, N_TOK / 128, 3), blk, 0, stream>>>(
        Ehi, Elo, Wqh, q_hi, q_lo, k_hi, vt, bq, bk, bv);

    // ---- chunked scores -> softmax -> PV(partials) -> reduce ----
    const int nchunks = N_TOK / NC;
    for (int c = 0; c < nchunks; c++) {
        const size_t roff = (size_t)c * NC;
        // S = q_c @ k^T (fp32 into Sc): 4-phase 256^2 kernel, folded K = 2*1024
        gemm8<EPI_F32, true, true, DIM, DIM><<<dim3(N_TOK / 256, NC / 256, 1), blk512, 0, stream>>>(
            q_hi + roff * DIM, q_lo + roff * DIM, k_hi, 32, Sc, N_TOK);
        // rowwise softmax: P=exp(s-m) fp16 in place (first half of each row), invl=1/sum
        softmax_rows<<<dim3(NC, 1, 1), blk, 0, stream>>>(Sc, invl + roff);
        // PV partials: 4-phase kernel, split-K=4 (32 K-tiles each), plain f32 stores
        gemm8<EPI_PART, false, true, 2 * N_TOK, N_TOK><<<dim3(DIM / 256, NC / 256, KS), blk512, 0, stream>>>(
            (const _Float16*)Sc, nullptr, vt, 32, Sc + N_TOK / 2, N_TOK);
        // out_c = invl * sum_z partials
        reduce_pv<<<dim3(NC, 1, 1), blk, 0, stream>>>(Sc, invl + roff, out + roff * DIM);
    }
}

// Round 10
// 641.441 us; speedup vs baseline: 1.0837x; 1.0837x over previous
//
#include <hip/hip_runtime.h>
#include <hip/hip_fp16.h>
#include <cstdint>
#include <cstddef>

typedef _Float16 half8 __attribute__((ext_vector_type(8)));
typedef _Float16 half4 __attribute__((ext_vector_type(4)));
typedef float floatx4 __attribute__((ext_vector_type(4)));
typedef float floatx16 __attribute__((ext_vector_type(16)));

#define N_TOK 8192
#define DIM   1024

#define EPI_F32   0   // C fp32 = acc                          (S = q k^T)
#define EPI_PART  1   // C fp32 partial at [row*ldc + bz*DIM + col]  (PV split-K)

#define FENCE_BARRIER() asm volatile("s_barrier" ::: "memory")
#define WAIT_VM4()      asm volatile("s_waitcnt vmcnt(4)" ::: "memory")
#define WAIT_VM0()      asm volatile("s_waitcnt vmcnt(0)" ::: "memory")

__device__ __forceinline__ void async_tile16(const _Float16* gp, _Float16* lp) {
    __builtin_amdgcn_global_load_lds(
        (const __attribute__((address_space(1))) void*)gp,
        (__attribute__((address_space(3))) void*)lp, 16, 0, 0);
}

// ---------------------------------------------------------------------------
// 256x256 tile, BK=64, 8 waves (2M x 4N), 512 threads, 16x16x32 MFMA
// (v8's 32x32 shape REVERTED: regressed 135->145, coarser MFMA blocks the
// wave longer and de-interleaves ds_read/MFMA).
// v9 FOLD path = B-SHARED fold: iteration i = {hi(i), lo(i)} — both multiply
// THE SAME k-tile B(i). B staged once/iter and bf registers reused across
// both halves: staging 16->12 loads/iter, LDS reads 32->24/iter, B1 dead.
//   P1: stage A1<-lo(i)   [A1 last read prev P4]; read B0 all + A0 m0-3; 32 MFMA
//   P2: stage B0<-B(i+1)  [B0 last read P1];      read A0 m4-7; 32 MFMA; vm4 (A1)
//   P3: stage A0<-hi(i+1) [A0 last read P2];      read A1 m0-3 (bf reused); 32 MFMA
//   P4:                                           read A1 m4-7; 32 MFMA; vm0 (B0,A0)
// Accumulation order hi(i),lo(i) interleaved = round-0 ASPLIT order.
// Non-FOLD (PV) path: v7 4-phase loop verbatim.
// NT GEMM: C[m][n] = sum_k A[m][k]*B[n][k].
// ---------------------------------------------------------------------------
template<int EPI, bool FOLD, bool REMAP, int LDA, int LDB>
__global__ __launch_bounds__(512)
void gemm8(const _Float16* __restrict__ Ahi, const _Float16* __restrict__ Alo,
           const _Float16* __restrict__ B, int ntiles,
           float* __restrict__ C, int ldc)
{
    __shared__ _Float16 smem[65536];          // 128 KiB (FOLD uses 96 KiB)

    int bx = blockIdx.x, by = blockIdx.y, bz = blockIdx.z;
    if constexpr (REMAP) {
        const int gx = gridDim.x, gy = gridDim.y;
        const int gxy = gx * gy;
        const int nb = gxy * gridDim.z;
        const int bid = bz * gxy + by * gx + bx;
        const int nid = (bid & 7) * (nb >> 3) + (bid >> 3);
        bx = nid % gx; by = (nid / gx) % gy; bz = nid / gxy;
    }

    const int tid  = threadIdx.x;
    const int lane = tid & 63;
    const int w    = tid >> 6;
    const int wm   = w >> 2;                  // 0..1 -> 128-row half
    const int wn   = w & 3;                   // 0..3 -> 64-col slice
    const int l15  = lane & 15;
    const int l4   = lane >> 4;               // 0..3
    const int row0 = by * 256;
    const int col0 = bx * 256;
    const int kbeg_t = FOLD ? 0 : bz * ntiles;

    const int r_s = tid >> 3;                 // staging row within 64-row pass
    const int j_s = tid & 7;                  // staging 16B chunk

    _Float16* A0 = smem;                      // buf0 A (256x64)
    _Float16* B0 = smem + 16384;              // B buffer (FOLD: single)
    _Float16* A1 = smem + 32768;              // buf1 A
    _Float16* B1 = smem + 49152;              // buf1 B (non-FOLD only)

    // read-side swizzled chunk offsets (halves), constant per lane
    const int co0 = ((l4)     ^ (l15 >> 1)) << 3;
    const int co1 = ((4 + l4) ^ (l15 >> 1)) << 3;

    floatx4 acc[8][4];
#pragma unroll
    for (int mi = 0; mi < 8; mi++)
#pragma unroll
        for (int ni = 0; ni < 4; ni++)
#pragma unroll
            for (int e = 0; e < 4; e++) acc[mi][ni][e] = 0.f;

    half8 af[4][2], bf[4][2];

    // stage one 128x64 half-tile (2 x global_load_lds dwordx4 per thread)
    auto stageA = [&](const _Float16* tile, int half, _Float16* reg) {
#pragma unroll
        for (int p = 0; p < 2; p++) {
            const int r  = half * 128 + p * 64 + r_s;
            const int jg = j_s ^ ((r >> 1) & 7);
            async_tile16(tile + (size_t)r * LDA + jg * 8, reg + r * 64 + j_s * 8);
        }
    };
    auto stageB = [&](const _Float16* tile, int half, _Float16* reg) {
#pragma unroll
        for (int p = 0; p < 2; p++) {
            const int r  = half * 128 + p * 64 + r_s;
            const int jg = j_s ^ ((r >> 1) & 7);
            async_tile16(tile + (size_t)r * LDB + jg * 8, reg + r * 64 + j_s * 8);
        }
    };

    auto lda4 = [&](const _Float16* Ab, int mbase) {     // a-frags mi mbase..+3, kk 0..1
#pragma unroll
        for (int m2 = 0; m2 < 4; m2++) {
            const int r = (wm * 128 + (mbase + m2) * 16 + l15) * 64;
            af[m2][0] = *(const half8*)&Ab[r + co0];
            af[m2][1] = *(const half8*)&Ab[r + co1];
        }
    };
    auto ldb2 = [&](const _Float16* Bb, int nbase) {     // b-frags ni nbase..+1, kk 0..1
#pragma unroll
        for (int n2 = 0; n2 < 2; n2++) {
            const int r = (wn * 64 + (nbase + n2) * 16 + l15) * 64;
            bf[nbase + n2][0] = *(const half8*)&Bb[r + co0];
            bf[nbase + n2][1] = *(const half8*)&Bb[r + co1];
        }
    };
    auto quad = [&](int qm, int qn) {                    // 16 MFMA: one C-quadrant x K=64
        __builtin_amdgcn_s_setprio(1);
#pragma unroll
        for (int kk = 0; kk < 2; kk++)
#pragma unroll
            for (int m2 = 0; m2 < 4; m2++)
#pragma unroll
                for (int n2 = 0; n2 < 2; n2++)
                    acc[qm * 4 + m2][qn * 2 + n2] =
                        __builtin_amdgcn_mfma_f32_16x16x32_f16(
                            af[m2][kk], bf[qn * 2 + n2][kk],
                            acc[qm * 4 + m2][qn * 2 + n2], 0, 0, 0);
        __builtin_amdgcn_s_setprio(0);
    };

    if constexpr (FOLD) {
        // ---- B-shared fold: 16 iterations, each = {hi(i), lo(i)} x B(i) ----
        auto hsrc = [&](int j) -> const _Float16* {
            j = j > 15 ? 15 : j;
            return Ahi + (size_t)row0 * LDA + j * 64;
        };
        auto lsrc = [&](int j) -> const _Float16* {
            j = j > 15 ? 15 : j;
            return Alo + (size_t)row0 * LDA + j * 64;
        };
        auto bsf = [&](int j) -> const _Float16* {
            j = j > 15 ? 15 : j;
            return B + (size_t)col0 * LDB + (size_t)j * 64;
        };

        // prologue: B0 <- B(0), A0 <- hi(0)
        stageB(bsf(0), 0, B0); stageB(bsf(0), 1, B0);
        stageA(hsrc(0), 0, A0); stageA(hsrc(0), 1, A0);
        WAIT_VM0();
        FENCE_BARRIER();

        for (int i = 0; i < 16; i++) {
            // P1: stage A1<-lo(i); read B0 all + A0 m0-3; 32 MFMA (hi, m0-3)
            stageA(lsrc(i), 0, A1); stageA(lsrc(i), 1, A1);
            ldb2(B0, 0); ldb2(B0, 2); lda4(A0, 0);
            quad(0, 0); quad(0, 1);
            FENCE_BARRIER();
            // P2: stage B0<-B(i+1); read A0 m4-7; 32 MFMA (hi, m4-7); certify A1
            stageB(bsf(i + 1), 0, B0); stageB(bsf(i + 1), 1, B0);
            lda4(A0, 4);
            quad(1, 0); quad(1, 1);
            WAIT_VM4(); FENCE_BARRIER();
            // P3: stage A0<-hi(i+1); read A1 m0-3 (bf REUSED); 32 MFMA (lo, m0-3)
            stageA(hsrc(i + 1), 0, A0); stageA(hsrc(i + 1), 1, A0);
            lda4(A1, 0);
            quad(0, 0); quad(0, 1);
            FENCE_BARRIER();
            // P4: read A1 m4-7; 32 MFMA (lo, m4-7); drain -> certify B0,A0 for next P1
            lda4(A1, 4);
            quad(1, 0); quad(1, 1);
            WAIT_VM0(); FENCE_BARRIER();
        }
    } else {
        // ---- v7 4-phase loop (PV), verbatim ----
        auto asrc = [&](int kt) -> const _Float16* {
            int ktc = kt > ntiles - 1 ? ntiles - 1 : kt;
            return Ahi + (size_t)row0 * LDA + (size_t)(kbeg_t + ktc) * 64;
        };
        auto bsrc = [&](int kt) -> const _Float16* {
            int ktc = kt > ntiles - 1 ? ntiles - 1 : kt;
            return B + (size_t)col0 * LDB + (size_t)(kbeg_t + ktc) * 64;
        };

        stageB(bsrc(0), 0, B0); stageB(bsrc(0), 1, B0);
        stageA(asrc(0), 0, A0); stageA(asrc(0), 1, A0);
        stageB(bsrc(1), 0, B1); stageB(bsrc(1), 1, B1);
        WAIT_VM4();
        FENCE_BARRIER();

        const int NIc = ntiles >> 1;
        for (int i = 0; i < NIc; i++) {
            const int t1 = 2 * i + 1, t2 = 2 * i + 2, t3 = 2 * i + 3;
            // P1: stage A1(t1) full; read B0 all + A0 m0-3; 32 MFMA
            stageA(asrc(t1), 0, A1); stageA(asrc(t1), 1, A1);
            ldb2(B0, 0); ldb2(B0, 2); lda4(A0, 0);
            quad(0, 0); quad(0, 1);
            FENCE_BARRIER();
            // P2: stage B0(t2) full; read A0 m4-7; 32 MFMA; gate {B1,A1}(t1)
            stageB(bsrc(t2), 0, B0); stageB(bsrc(t2), 1, B0);
            lda4(A0, 4);
            quad(1, 0); quad(1, 1);
            WAIT_VM4(); FENCE_BARRIER();
            // P3: stage A0(t2) full; read B1 all + A1 m0-3; 32 MFMA
            stageA(asrc(t2), 0, A0); stageA(asrc(t2), 1, A0);
            ldb2(B1, 0); ldb2(B1, 2); lda4(A1, 0);
            quad(0, 0); quad(0, 1);
            FENCE_BARRIER();
            // P4: stage B1(t3) full; read A1 m4-7; 32 MFMA; gate {B0,A0}(t2)
            stageB(bsrc(t3), 0, B1); stageB(bsrc(t3), 1, B1);
            lda4(A1, 4);
            quad(1, 0); quad(1, 1);
            WAIT_VM4(); FENCE_BARRIER();
        }
    }
    WAIT_VM0();

    // epilogue. 16x16 C/D layout: col = lane&15, row = (lane>>4)*4 + reg
#pragma unroll
    for (int mi = 0; mi < 8; mi++) {
#pragma unroll
        for (int ni = 0; ni < 4; ni++) {
            const int row = row0 + wm * 128 + mi * 16 + l4 * 4;
            const int col = col0 + wn * 64 + ni * 16 + l15;
#pragma unroll
            for (int r2 = 0; r2 < 4; r2++) {
                const float v = acc[mi][ni][r2];
                if constexpr (EPI == EPI_F32) {
                    C[(size_t)(row + r2) * ldc + col] = v;
                } else {
                    C[(size_t)(row + r2) * ldc + (size_t)bz * DIM + col] = v;
                }
            }
        }
    }
}

// ---------------------------------------------------------------------------
// Fused QKV projection (proven structure): grid.z = unit (0=q HILO, 1=k HI,
// 2=v VT). B = stacked [3*DIM][DIM] fp16 weights. 128x128 tile, BK=64.
// ---------------------------------------------------------------------------
template<int BM, int BN, int BK>
__global__ __launch_bounds__(256)
void gemm_qkv(const _Float16* __restrict__ Ehi, const _Float16* __restrict__ Elo,
              const _Float16* __restrict__ W,
              _Float16* __restrict__ qhi, _Float16* __restrict__ qlo,
              _Float16* __restrict__ khi, _Float16* __restrict__ vtr,
              const float* __restrict__ bq, const float* __restrict__ bk,
              const float* __restrict__ bv)
{
    constexpr int MI = BM / 64;
    constexpr int NI = BN / 64;
    constexpr int CPR = BK / 8;
    constexpr int SW  = CPR - 1;
    constexpr int RPP = 2048 / BK;
    constexpr int IA  = BM * BK / 2048;
    constexpr int IB  = BN * BK / 2048;
    constexpr int A_ELTS = BM * BK;
    constexpr int B_ELTS = BN * BK;
    __shared__ _Float16 smem[2 * A_ELTS + B_ELTS];
    constexpr int tAhi = 0;
    constexpr int tAlo = A_ELTS;
    constexpr int tB   = 2 * A_ELTS;

    int bx = blockIdx.x, by = blockIdx.y, bz = blockIdx.z;
    {
        const int gx = gridDim.x, gy = gridDim.y;
        const int gxy = gx * gy;
        const int nb = gxy * gridDim.z;
        const int bid = bz * gxy + by * gx + bx;
        const int nid = (bid & 7) * (nb >> 3) + (bid >> 3);
        bx = nid % gx; by = (nid / gx) % gy; bz = nid / gxy;
    }
    const int unit = bz;
    const bool dolo = (unit < 2);

    const int tid  = threadIdx.x;
    const int row0 = by * BM;
    const int col0 = bx * BN;
    const int lane = tid & 63;
    const int w    = tid >> 6;
    const int wm   = w & 1, wn = w >> 1;
    const int l31  = lane & 31, lhi = lane >> 5;

    floatx16 acc[MI][NI];
#pragma unroll
    for (int mi = 0; mi < MI; mi++)
#pragma unroll
        for (int ni = 0; ni < NI; ni++)
#pragma unroll
            for (int e = 0; e < 16; e++) acc[mi][ni][e] = 0.f;

    const int r_s = tid / CPR;
    const int j_s = tid % CPR;
    const size_t brow0 = (size_t)(unit * DIM + col0);

    for (int k0 = 0; k0 < DIM; k0 += BK) {
        __syncthreads();
#pragma unroll
        for (int i = 0; i < IA; i++) {
            const int r = i * RPP + r_s;
            const int jg = j_s ^ ((r >> 1) & SW);
            async_tile16(Ehi + (size_t)(row0 + r) * DIM + k0 + jg * 8,
                         smem + tAhi + (i * 256 + tid) * 8);
            if (dolo)
                async_tile16(Elo + (size_t)(row0 + r) * DIM + k0 + jg * 8,
                             smem + tAlo + (i * 256 + tid) * 8);
        }
#pragma unroll
        for (int i = 0; i < IB; i++) {
            const int r = i * RPP + r_s;
            const int jg = j_s ^ ((r >> 1) & SW);
            async_tile16(W + (brow0 + r) * DIM + k0 + jg * 8,
                         smem + tB + (i * 256 + tid) * 8);
        }
        __syncthreads();

#pragma unroll
        for (int ks = 0; ks < BK / 16; ks++) {
            half8 af[MI], bf[NI], al[MI];
            const int cb = ks * 2 + lhi;
#pragma unroll
            for (int mi = 0; mi < MI; mi++) {
                const int r = wm * (BM / 2) + mi * 32 + l31;
                const int cj = (cb ^ ((r >> 1) & SW)) * 8;
                af[mi] = *(half8*)&smem[tAhi + r * BK + cj];
                if (dolo) al[mi] = *(half8*)&smem[tAlo + r * BK + cj];
            }
#pragma unroll
            for (int ni = 0; ni < NI; ni++) {
                const int r = wn * (BN / 2) + ni * 32 + l31;
                const int cj = (cb ^ ((r >> 1) & SW)) * 8;
                bf[ni] = *(half8*)&smem[tB + r * BK + cj];
            }
#pragma unroll
            for (int mi = 0; mi < MI; mi++)
#pragma unroll
                for (int ni = 0; ni < NI; ni++)
                    acc[mi][ni] = __builtin_amdgcn_mfma_f32_32x32x16_f16(af[mi], bf[ni], acc[mi][ni], 0, 0, 0);
            if (dolo) {
#pragma unroll
                for (int mi = 0; mi < MI; mi++)
#pragma unroll
                    for (int ni = 0; ni < NI; ni++)
                        acc[mi][ni] = __builtin_amdgcn_mfma_f32_32x32x16_f16(al[mi], bf[ni], acc[mi][ni], 0, 0, 0);
            }
        }
    }

    const float* bias = (unit == 0) ? bq : (unit == 1) ? bk : bv;
#pragma unroll
    for (int mi = 0; mi < MI; mi++) {
#pragma unroll
        for (int ni = 0; ni < NI; ni++) {
            const int colg = col0 + wn * (BN / 2) + ni * 32 + l31;
            const float bb = bias[colg];
            const int base = row0 + wm * (BM / 2) + mi * 32 + 4 * lhi;
#pragma unroll
            for (int g = 0; g < 4; g++) {
                const int rowb = base + 8 * g;
                if (unit == 2) {
                    half4 hv;
#pragma unroll
                    for (int r2 = 0; r2 < 4; r2++) hv[r2] = (_Float16)(acc[mi][ni][4 * g + r2] + bb);
                    *(half4*)&vtr[(size_t)colg * N_TOK + rowb] = hv;
                } else {
#pragma unroll
                    for (int r2 = 0; r2 < 4; r2++) {
                        const int rowg = rowb + r2;
                        const float t = acc[mi][ni][4 * g + r2] + bb;
                        const _Float16 hi = (_Float16)t;
                        if (unit == 0) {
                            qhi[(size_t)rowg * DIM + colg] = hi;
                            qlo[(size_t)rowg * DIM + colg] = (_Float16)(t - (float)hi);
                        } else {
                            khi[(size_t)rowg * DIM + colg] = hi;
                        }
                    }
                }
            }
        }
    }
}

// fp32 -> fp16 hi (+lo) pre-split. grid.y = unit: 0..7 = E chunks, 8/9/10 = Wq/Wk/Wv.
__global__ __launch_bounds__(256)
void split_inputs(const float* __restrict__ E,
                  const float* __restrict__ Wq, const float* __restrict__ Wk, const float* __restrict__ Wv,
                  _Float16* __restrict__ Ehi, _Float16* __restrict__ Elo,
                  _Float16* __restrict__ Wqh, _Float16* __restrict__ Wkh, _Float16* __restrict__ Wvh)
{
    const int u = blockIdx.y;
    const size_t idx = ((size_t)blockIdx.x * 256 + threadIdx.x) * 4;
    const size_t MM = (size_t)DIM * DIM;
    const float* src; _Float16* dhi; _Float16* dlo = nullptr;
    if (u < 8)      { src = E + u * MM;  dhi = Ehi + u * MM; dlo = Elo + u * MM; }
    else if (u == 8){ src = Wq; dhi = Wqh; }
    else if (u == 9){ src = Wk; dhi = Wkh; }
    else            { src = Wv; dhi = Wvh; }
    const float4 f = *(const float4*)(src + idx);
    half4 hh;
    hh[0] = (_Float16)f.x; hh[1] = (_Float16)f.y; hh[2] = (_Float16)f.z; hh[3] = (_Float16)f.w;
    *(half4*)(dhi + idx) = hh;
    if (u < 8) {
        half4 hl;
        hl[0] = (_Float16)(f.x - (float)hh[0]); hl[1] = (_Float16)(f.y - (float)hh[1]);
        hl[2] = (_Float16)(f.z - (float)hh[2]); hl[3] = (_Float16)(f.w - (float)hh[3]);
        *(half4*)(dlo + idx) = hl;
    }
}

// One block per row. Row held in REGISTERS (8 x float4 per thread, static
// indices). P = exp(s-m) fp16 in place, inv_l = 1/sum.
__global__ __launch_bounds__(256)
void softmax_rows(float* __restrict__ S, float* __restrict__ inv_l)
{
    __shared__ float red[4];
    const int tid = threadIdx.x;
    float* row = S + (size_t)blockIdx.x * N_TOK;

    float4 v0, v1, v2, v3, v4, v5, v6, v7;
    float mx = -3.0e38f;
#define LOADMAX(VV, I) \
    VV = ((const float4*)row)[(I) * 256 + tid]; \
    mx = fmaxf(mx, fmaxf(fmaxf(VV.x, VV.y), fmaxf(VV.z, VV.w)));
    LOADMAX(v0, 0) LOADMAX(v1, 1) LOADMAX(v2, 2) LOADMAX(v3, 3)
    LOADMAX(v4, 4) LOADMAX(v5, 5) LOADMAX(v6, 6) LOADMAX(v7, 7)
#undef LOADMAX
#pragma unroll
    for (int off = 32; off > 0; off >>= 1) mx = fmaxf(mx, __shfl_down(mx, off));
    if ((tid & 63) == 0) red[tid >> 6] = mx;
    __syncthreads();
    mx = fmaxf(fmaxf(red[0], red[1]), fmaxf(red[2], red[3]));
    __syncthreads();

    float sum = 0.f;
    _Float16* prow = (_Float16*)row;
#define EXPSTORE(VV, I) { \
    const float e0 = __expf(VV.x - mx), e1 = __expf(VV.y - mx); \
    const float e2 = __expf(VV.z - mx), e3 = __expf(VV.w - mx); \
    sum += (e0 + e1) + (e2 + e3); \
    half4 h; h[0] = (_Float16)e0; h[1] = (_Float16)e1; h[2] = (_Float16)e2; h[3] = (_Float16)e3; \
    ((half4*)prow)[(I) * 256 + tid] = h; }
    EXPSTORE(v0, 0) EXPSTORE(v1, 1) EXPSTORE(v2, 2) EXPSTORE(v3, 3)
    EXPSTORE(v4, 4) EXPSTORE(v5, 5) EXPSTORE(v6, 6) EXPSTORE(v7, 7)
#undef EXPSTORE
#pragma unroll
    for (int off = 32; off > 0; off >>= 1) sum += __shfl_down(sum, off);
    if ((tid & 63) == 0) red[tid >> 6] = sum;
    __syncthreads();
    if (tid == 0) inv_l[blockIdx.x] = 1.f / (red[0] + red[1] + red[2] + red[3]);
}

// out[r][c] = invl[r] * sum_z partial[z][r][c]; partials in float offsets [4096,8192)
// of each Sc row. One block per row.
__global__ __launch_bounds__(256)
void reduce_pv(const float* __restrict__ Sc, const float* __restrict__ invl,
               float* __restrict__ out)
{
    const int r  = blockIdx.x;
    const int c4 = threadIdx.x;
    const float* p = Sc + (size_t)r * N_TOK + N_TOK / 2 + (size_t)c4 * 4;
    float4 s = *(const float4*)p;
#pragma unroll
    for (int z = 1; z < 4; z++) {
        const float4 t = *(const float4*)(p + (size_t)z * DIM);
        s.x += t.x; s.y += t.y; s.z += t.z; s.w += t.w;
    }
    const float iv = invl[r];
    float4 o; o.x = s.x * iv; o.y = s.y * iv; o.z = s.z * iv; o.w = s.w * iv;
    *(float4*)(out + (size_t)r * DIM + (size_t)c4 * 4) = o;
}

extern "C" void kernel_launch(void* const* d_in, const int* in_sizes, int n_in,
                              void* d_out, int out_size, void* d_ws, size_t ws_size,
                              hipStream_t stream)
{
    const float* E  = (const float*)d_in[0];
    const float* Wq = (const float*)d_in[1];
    const float* bq = (const float*)d_in[2];
    const float* Wk = (const float*)d_in[3];
    const float* bk = (const float*)d_in[4];
    const float* Wv = (const float*)d_in[5];
    const float* bv = (const float*)d_in[6];
    float* out = (float*)d_out;

    char* ws = (char*)d_ws;
    const size_t SZ = (size_t)N_TOK * DIM * sizeof(_Float16);   // 16 MiB
    const size_t WW = (size_t)DIM * DIM * sizeof(_Float16);     // 2 MiB
    _Float16* q_hi = (_Float16*)(ws);
    _Float16* q_lo = (_Float16*)(ws + SZ);
    _Float16* k_hi = (_Float16*)(ws + 2 * SZ);
    _Float16* vt   = (_Float16*)(ws + 3 * SZ);
    float*    invl = (float*)(ws + 4 * SZ);
    char*     scratch = ws + 4 * SZ + 65536;
    _Float16* Ehi = (_Float16*)(scratch);
    _Float16* Elo = (_Float16*)(scratch + SZ);
    _Float16* Wqh = (_Float16*)(scratch + 2 * SZ);              // Wqh,Wkh,Wvh contiguous
    _Float16* Wkh = (_Float16*)(scratch + 2 * SZ + WW);
    _Float16* Wvh = (_Float16*)(scratch + 2 * SZ + 2 * WW);
    float*    Sc  = (float*)(scratch);
    const size_t esplit_bytes = 2 * SZ + 3 * WW;
    const size_t base = 4 * SZ + 65536;

    int NC = 256;
    const int cands[6] = {8192, 4096, 2048, 1024, 512, 256};
    for (int i = 0; i < 6; i++) {
        size_t sc = (size_t)cands[i] * N_TOK * 4;
        size_t need = base + (sc > esplit_bytes ? sc : esplit_bytes);
        if (ws_size >= need) { NC = cands[i]; break; }
    }

    const dim3 blk(256, 1, 1);
    const dim3 blk512(512, 1, 1);
    constexpr int KS = 4;                  // PV split-K factor

    // ---- pre-split: E -> hi/lo fp16, W -> hi fp16 ----
    split_inputs<<<dim3(DIM * DIM / 1024, 11, 1), blk, 0, stream>>>(
        E, Wq, Wk, Wv, Ehi, Elo, Wqh, Wkh, Wvh);

    // ---- fused QKV projection: one dispatch, 3 units on grid.z ----
    gemm_qkv<128, 128, 64><<<dim3(DIM / 128, N_TOK / 128, 3), blk, 0, stream>>>(
        Ehi, Elo, Wqh, q_hi, q_lo, k_hi, vt, bq, bk, bv);

    // ---- chunked scores -> softmax -> PV(partials) -> reduce ----
    const int nchunks = N_TOK / NC;
    for (int c = 0; c < nchunks; c++) {
        const size_t roff = (size_t)c * NC;
        // S = q_c @ k^T (fp32 into Sc): B-shared-fold 4-phase 256^2 kernel
        gemm8<EPI_F32, true, true, DIM, DIM><<<dim3(N_TOK / 256, NC / 256, 1), blk512, 0, stream>>>(
            q_hi + roff * DIM, q_lo + roff * DIM, k_hi, 32, Sc, N_TOK);
        // rowwise softmax: P=exp(s-m) fp16 in place (first half of each row), invl=1/sum
        softmax_rows<<<dim3(NC, 1, 1), blk, 0, stream>>>(Sc, invl + roff);
        // PV partials: v7 4-phase kernel, split-K=4 (32 K-tiles each), plain f32 stores
        gemm8<EPI_PART, false, true, 2 * N_TOK, N_TOK><<<dim3(DIM / 256, NC / 256, KS), blk512, 0, stream>>>(
            (const _Float16*)Sc, nullptr, vt, 32, Sc + N_TOK / 2, N_TOK);
        // out_c = invl * sum_z partials
        reduce_pv<<<dim3(NC, 1, 1), blk, 0, stream>>>(Sc, invl + roff, out + roff * DIM);
    }
}